// Round 1
// 375.988 us; speedup vs baseline: 1.0847x; 1.0847x over previous
//
#include <hip/hip_runtime.h>
#include <math.h>

// Problem constants (from reference): B=16, T=128, U=32 (acts has U+1=33), V=1024
#define RB 16
#define RT 128
#define RU 32
#define RV 1024
#define NROWS (RB * RT * (RU + 1))   // 67584

// ---------------------------------------------------------------------------
// Kernel 1: per-(b,t,u) row logsumexp over V, then write
//   blank_ws[b,t,u] = acts[b,t,u,blank]      - lse
//   emit_ws [b,t,u] = acts[b,t,u,label[b,u]] - lse   (u < U only)
// One wave (64 lanes) per row; 4 x float4 per lane covers 1024 floats.
// Rows with t >= T_b or u > U_b are never used by the DP -> early-exit
// before the HBM loads (cuts fetched bytes from 277 MB to ~160 MB).
//
// This revision:
//  - ONE coalesced 64B load serves both length arrays (lanes 0-15 ->
//    label_lens, lanes 16-31 -> act_lens) + shfl broadcast; removes a
//    second dependent VMEM load from every wave's prologue.
//  - labels[idx] / base[lab] / base[blank] are issued as wave-uniform
//    broadcast loads BETWEEN the max-reduce and exp/sum phases, so their
//    dependent-load latency hides under the reduction instead of adding
//    a serial tail after it.
// ---------------------------------------------------------------------------
__global__ __launch_bounds__(256) void rnnt_lse_kernel(
    const float* __restrict__ acts,
    const int*   __restrict__ labels,
    const int*   __restrict__ act_lens,
    const int*   __restrict__ label_lens,
    const int*   __restrict__ blank_p,
    float* __restrict__ blank_ws,
    float* __restrict__ emit_ws,
    int n_labels)
{
    const int tid  = threadIdx.x;
    const int lane = tid & 63;
    const int wave = tid >> 6;
    const int row  = blockIdx.x * 4 + wave;   // grid sized so row < NROWS

    // decode (b, t, u); RT=128 and RU+1=33
    const int u  = row % (RU + 1);
    const int rt = row / (RU + 1);
    const int t  = rt & (RT - 1);
    const int b  = rt >> 7;

    // single coalesced load covering both length arrays
    int lv = 0;
    if (lane < 32) {
        const int* p = (lane < 16) ? (label_lens + lane) : (act_lens + (lane - 16));
        lv = *p;
    }
    const int Ub = __shfl(lv, b);
    const int Tb = __shfl(lv, 16 + b);
    if (t >= Tb || u > Ub) return;     // row never consumed by the DP

    // bulk row loads: issue ASAP (memory-bound kernel)
    const float*  base = acts + (size_t)row * RV;
    const float4* b4   = (const float4*)base;
    float4 x0 = b4[lane];
    float4 x1 = b4[lane + 64];
    float4 x2 = b4[lane + 128];
    float4 x3 = b4[lane + 192];

    // cum[b] = sum_{j<b} label_lens[j] via 16-lane shfl prefix scan
    // (shfl = LDS pipe; overlaps the in-flight VMEM above)
    int pls = (lane < 16) ? lv : 0;
    #pragma unroll
    for (int off = 1; off < 16; off <<= 1) {
        int n = __shfl_up(pls, off);
        if (lane >= off) pls += n;
    }
    const int cum = (b == 0) ? 0 : __shfl(pls, b - 1);

    int idx = cum + u;
    idx = min(max(idx, 0), n_labels - 1);
    const int lab   = labels[idx];     // wave-uniform broadcast load
    const int blank = blank_p[0];      // broadcast (L1/L2 resident)

    float m = fmaxf(fmaxf(fmaxf(x0.x, x0.y), fmaxf(x0.z, x0.w)),
                    fmaxf(fmaxf(x1.x, x1.y), fmaxf(x1.z, x1.w)));
    m = fmaxf(m, fmaxf(fmaxf(fmaxf(x2.x, x2.y), fmaxf(x2.z, x2.w)),
                       fmaxf(fmaxf(x3.x, x3.y), fmaxf(x3.z, x3.w))));
    #pragma unroll
    for (int off = 32; off > 0; off >>= 1)
        m = fmaxf(m, __shfl_xor(m, off));

    // issue the two scalar picks here; their latency hides under the
    // exp/sum phase below (lines are L1/L2-hot: just streamed by this wave)
    const float bl = base[blank];
    const float el = base[lab];

    // 4 independent accumulators for exp-sum ILP
    float s0 = __expf(x0.x - m) + __expf(x0.y - m) + __expf(x0.z - m) + __expf(x0.w - m);
    float s1 = __expf(x1.x - m) + __expf(x1.y - m) + __expf(x1.z - m) + __expf(x1.w - m);
    float s2 = __expf(x2.x - m) + __expf(x2.y - m) + __expf(x2.z - m) + __expf(x2.w - m);
    float s3 = __expf(x3.x - m) + __expf(x3.y - m) + __expf(x3.z - m) + __expf(x3.w - m);
    float s = (s0 + s1) + (s2 + s3);
    #pragma unroll
    for (int off = 32; off > 0; off >>= 1)
        s += __shfl_xor(s, off);

    if (lane == 0) {
        const float lse = m + __logf(s);
        blank_ws[row] = bl - lse;
        if (u < RU)
            emit_ws[((size_t)b * RT + t) * RU + u] = el - lse;
    }
}

// ---------------------------------------------------------------------------
// Kernel 2: per-batch forward DP (anti-diagonal wavefront in one wave).
//   alpha[t][u] = logaddexp(alpha[t-1][u] + blank[t-1][u],
//                           alpha[t][u-1] + emit[t][u-1])
// LDS rows padded to 34 so the skewed access (lane stride 33 mod 32 = 1)
// is bank-conflict-free.
// This revision:
//  - staging bounded by T_b (rows t >= T_b were never written by kernel 1
//    and are never read by the DP -> skip the poison reads),
//  - logaddexp tail uses __logf(1+z) (single v_log_f32) instead of the
//    multi-instruction log1pf libm path: shortens the 160-step serial
//    dependence chain. z = exp(min-max) in (0,1], so no cancellation;
//    abs error ~6e-8 per step.
// ---------------------------------------------------------------------------
__global__ __launch_bounds__(256) void rnnt_dp_kernel(
    const float* __restrict__ blank_ws,
    const float* __restrict__ emit_ws,
    const int*   __restrict__ act_lens,
    const int*   __restrict__ label_lens,
    float* __restrict__ out)
{
    __shared__ float sb[RT * 34];   // blank, [t][u] u<33, padded
    __shared__ float se[RT * 34];   // emit,  [t][u] u<32, padded

    const int b   = blockIdx.x;
    const int tid = threadIdx.x;
    const int Tb  = act_lens[b];      // broadcast load, all threads
    const float* gb = blank_ws + (size_t)b * RT * (RU + 1);
    const float* ge = emit_ws  + (size_t)b * RT * RU;

    const int nb = Tb * (RU + 1);
    for (int i = tid; i < nb; i += 256) {
        int t = i / (RU + 1), u = i - t * (RU + 1);
        sb[t * 34 + u] = gb[i];
    }
    const int ne = Tb * RU;
    for (int i = tid; i < ne; i += 256) {
        int t = i / RU, u = i - t * RU;
        se[t * 34 + u] = ge[i];
    }
    __syncthreads();

    if (tid < 64) {
        const int u  = tid;
        const int Ub = label_lens[b];

        // alpha[0][u] = sum_{j<u} emit[0][j]  (exclusive prefix via shfl scan)
        float v = (u >= 1 && u <= RU) ? se[u - 1] : 0.0f;
        #pragma unroll
        for (int off = 1; off < 64; off <<= 1) {
            float n = __shfl_up(v, off);
            if (u >= off) v += n;
        }
        float A  = v;      // lane u holds alpha[t][u], skewed over iterations
        float ll = 0.0f;

        const int smax = (Tb - 1) + Ub;
        for (int s = 1; s <= smax; ++s) {
            const float left = __shfl_up(A, 1);   // alpha[t][u-1]
            const int t = s - u;
            if (t >= 1 && t <= Tb - 1 && u <= RU) {
                const float ab = A + sb[(t - 1) * 34 + u];
                float nv;
                if (u == 0) {
                    nv = ab;
                } else {
                    const float ae = left + se[t * 34 + (u - 1)];
                    const float mx = fmaxf(ab, ae);
                    nv = mx + __logf(1.0f + __expf(fminf(ab, ae) - mx));
                }
                A = nv;
                if (t == Tb - 1 && u == Ub)
                    ll = A + sb[t * 34 + u];
            }
        }
        const float llb = __shfl(ll, Ub);
        if (u == 0) atomicAdd(out, -llb);
    }
}

extern "C" void kernel_launch(void* const* d_in, const int* in_sizes, int n_in,
                              void* d_out, int out_size, void* d_ws, size_t ws_size,
                              hipStream_t stream) {
    const float* acts       = (const float*)d_in[0];
    const int*   labels     = (const int*)d_in[1];
    const int*   act_lens   = (const int*)d_in[2];
    const int*   label_lens = (const int*)d_in[3];
    const int*   blank_p    = (const int*)d_in[4];
    float* out = (float*)d_out;

    const int n_labels = in_sizes[1];   // B*U = 512

    float* blank_ws = (float*)d_ws;                    // NROWS floats
    float* emit_ws  = blank_ws + NROWS;                // B*T*U floats

    hipMemsetAsync(out, 0, sizeof(float), stream);

    const int grid1 = NROWS / 4;   // 4 waves (rows) per 256-thread block
    rnnt_lse_kernel<<<grid1, 256, 0, stream>>>(
        acts, labels, act_lens, label_lens, blank_p, blank_ws, emit_ws, n_labels);

    rnnt_dp_kernel<<<RB, 256, 0, stream>>>(
        blank_ws, emit_ws, act_lens, label_lens, out);
}